// Round 1
// baseline (125.024 us; speedup 1.0000x reference)
//
#include <hip/hip_runtime.h>

// Problem constants (B,P,D,H,DB) = (2048,128,64,8,10)
#define NB   2048
#define NP   128
#define ND   64
#define NH   8
#define NDB  10
#define HD   512      // H*D
#define F2   1024     // 2*H*D
#define XQS  1536     // xproj(1024) ++ q(512) stride

// ---------------------------------------------------------------------------
// K1: XQ[b][0..1023] = x@W_kvx + b_kvx ; XQ[b][1024..1535] = x@W_q + b_q
// Tile: 64 batch rows x 64 feature cols, 256 threads, 4x4 register tile.
// ---------------------------------------------------------------------------
__global__ __launch_bounds__(256) void proj_kernel(
    const float* __restrict__ x, const float* __restrict__ W_kvx,
    const float* __restrict__ b_kvx, const float* __restrict__ W_q,
    const float* __restrict__ b_q, float* __restrict__ XQ)
{
    __shared__ float xs[64][68];   // [k][row], pad 68 keeps float4 align
    __shared__ float ws_[64][64];  // [k][col]
    const int rt = blockIdx.x;     // 0..31 row tile
    const int ct = blockIdx.y;     // 0..23 col tile (0..15 kvx, 16..23 q)
    const int row0 = rt * 64;
    const int t = threadIdx.x;

    // stage x tile transposed: xs[k][r] = x[row0+r][k]
    #pragma unroll
    for (int it = 0; it < 16; ++it) {
        int i = t + 256 * it;
        int r = i >> 6, k = i & 63;
        xs[k][r] = x[(row0 + r) * ND + k];
    }
    const float* Wsrc; const float* bsrc; int stride, col0;
    if (ct < 16) { Wsrc = W_kvx; bsrc = b_kvx; stride = F2; col0 = ct * 64; }
    else         { Wsrc = W_q;   bsrc = b_q;   stride = HD; col0 = (ct - 16) * 64; }
    #pragma unroll
    for (int it = 0; it < 16; ++it) {
        int i = t + 256 * it;
        int kr = i >> 6, c = i & 63;
        ws_[kr][c] = Wsrc[kr * stride + col0 + c];
    }
    __syncthreads();

    const int tr = t >> 4, tc = t & 15;   // 16x16 thread grid, 4x4 outputs each
    float acc[4][4] = {};
    for (int k = 0; k < 64; ++k) {
        float4 a = *(const float4*)&xs[k][tr * 4];
        float4 w = *(const float4*)&ws_[k][tc * 4];
        float av[4] = {a.x, a.y, a.z, a.w};
        float wv[4] = {w.x, w.y, w.z, w.w};
        #pragma unroll
        for (int i = 0; i < 4; ++i)
            #pragma unroll
            for (int j = 0; j < 4; ++j)
                acc[i][j] = fmaf(av[i], wv[j], acc[i][j]);
    }
    float4 bias = *(const float4*)&bsrc[col0 + tc * 4];
    const int outcol = ct * 64 + tc * 4;  // holds for both halves (1024 + (ct-16)*64 == ct*64)
    #pragma unroll
    for (int i = 0; i < 4; ++i) {
        float4 o;
        o.x = acc[i][0] + bias.x;
        o.y = acc[i][1] + bias.y;
        o.z = acc[i][2] + bias.z;
        o.w = acc[i][3] + bias.w;
        *(float4*)&XQ[(row0 + tr * 4 + i) * XQS + outcol] = o;
    }
}

// ---------------------------------------------------------------------------
// K2: per-batch fused attention core. One block (256 thr = 4 waves) per b.
//   dot0[h]   = sum_d (xp_k[h,d]+b_kvb[h,d]) * q[h,d]
//   Wqkb[e,h] = sum_d W_kvb[e,h*64+d] * q[h,d]
//   dots[p,h] = 0.125*(dot0[h] + sum_e bb[p,e]*Wqkb[e,h]) ; softmax over h
//   A[h] = sum_p attn ; S[e,h] = sum_p attn*bb[p,e]
//   vals[h,d] = A[h]*(xp_v+b_kvb) + sum_e S[e,h]*W_kvb[e,512+h*64+d]
// ---------------------------------------------------------------------------
__global__ __launch_bounds__(256) void attn_kernel(
    const float* __restrict__ bmat, const float* __restrict__ W_kvb,
    const float* __restrict__ b_kvb, const float* __restrict__ XQ,
    float* __restrict__ VALS)
{
    __shared__ float q_s[HD];
    __shared__ float bb_s[NP * NDB];     // 1280
    __shared__ float dot0[NH];
    __shared__ float Wqkb[NDB][NH];
    __shared__ float partA[4][NH];
    __shared__ float partS[4][NDB][NH];
    __shared__ float A_s[NH];
    __shared__ float S_s[NDB][NH];

    const int b = blockIdx.x;
    const int t = threadIdx.x;
    const int lane = t & 63, w = t >> 6;
    const float* xq = XQ + (size_t)b * XQS;

    q_s[t]       = xq[1024 + t];
    q_s[t + 256] = xq[1024 + t + 256];
    #pragma unroll
    for (int it = 0; it < 5; ++it) {
        int i = t + 256 * it;
        bb_s[i] = bmat[(size_t)b * (NP * NDB) + i];
    }
    __syncthreads();

    // dot0: two 512-elem passes, each wave reduces one h-segment of 64
    #pragma unroll
    for (int iter = 0; iter < 2; ++iter) {
        int f = t + iter * 256;
        float prod = (xq[f] + b_kvb[f]) * q_s[f];
        #pragma unroll
        for (int m = 32; m >= 1; m >>= 1) prod += __shfl_xor(prod, m);
        if (lane == 0) dot0[w + iter * 4] = prod;
    }
    // Wqkb: 80 outputs, one per 8-lane group (3 rounds)
    {
        int g = t >> 3, l = t & 7;
        #pragma unroll
        for (int ro = 0; ro < 3; ++ro) {
            int o = g + 32 * ro;
            if (o < 80) {
                int e = o >> 3, hh = o & 7;
                float s = 0.f;
                #pragma unroll
                for (int m = 0; m < 8; ++m) {
                    int d = l + m * 8;
                    s += W_kvb[e * F2 + hh * 64 + d] * q_s[hh * 64 + d];
                }
                #pragma unroll
                for (int mm = 1; mm <= 4; mm <<= 1) s += __shfl_xor(s, mm);
                if (l == 0) Wqkb[e][hh] = s;
            }
        }
    }
    __syncthreads();

    // dots + softmax(h) + accumulate A, S
    const int h = t & 7;
    const int pbase = t >> 3;  // 0..31
    float aA = 0.f;
    float aS[NDB];
    #pragma unroll
    for (int e = 0; e < NDB; ++e) aS[e] = 0.f;
    #pragma unroll
    for (int it = 0; it < 4; ++it) {
        int p = pbase + it * 32;
        float dot = dot0[h];
        #pragma unroll
        for (int e = 0; e < NDB; ++e) dot += bb_s[p * NDB + e] * Wqkb[e][h];
        dot *= 0.125f;
        float m = dot;
        #pragma unroll
        for (int mm = 1; mm <= 4; mm <<= 1) m = fmaxf(m, __shfl_xor(m, mm));
        float ex = __expf(dot - m);
        float s = ex;
        #pragma unroll
        for (int mm = 1; mm <= 4; mm <<= 1) s += __shfl_xor(s, mm);
        float at = ex / s;
        aA += at;
        #pragma unroll
        for (int e = 0; e < NDB; ++e) aS[e] += at * bb_s[p * NDB + e];
    }
    // reduce over p within wave (lanes sharing h are 8 apart)
    #pragma unroll
    for (int mm = 8; mm <= 32; mm <<= 1) aA += __shfl_xor(aA, mm);
    #pragma unroll
    for (int e = 0; e < NDB; ++e)
        #pragma unroll
        for (int mm = 8; mm <= 32; mm <<= 1) aS[e] += __shfl_xor(aS[e], mm);
    if (lane < 8) {
        partA[w][lane] = aA;
        #pragma unroll
        for (int e = 0; e < NDB; ++e) partS[w][e][lane] = aS[e];
    }
    __syncthreads();
    if (t < 8)  A_s[t] = partA[0][t] + partA[1][t] + partA[2][t] + partA[3][t];
    if (t < 80) {
        int e = t >> 3, hh = t & 7;
        S_s[e][hh] = partS[0][e][hh] + partS[1][e][hh] + partS[2][e][hh] + partS[3][e][hh];
    }
    __syncthreads();

    // vals
    #pragma unroll
    for (int iter = 0; iter < 2; ++iter) {
        int f = t + iter * 256;
        int hh = f >> 6;
        float val = A_s[hh] * (xq[512 + f] + b_kvb[512 + f]);
        #pragma unroll
        for (int e = 0; e < NDB; ++e) val += S_s[e][hh] * W_kvb[e * F2 + 512 + f];
        VALS[(size_t)b * HD + f] = val;
    }
}

// ---------------------------------------------------------------------------
// K3: out = vals @ W_f + b_f   ([2048,512]@[512,64])
// 256 blocks x 8 rows; W_f rows broadcast via L1; vals staged in LDS.
// ---------------------------------------------------------------------------
__global__ __launch_bounds__(256) void out_kernel(
    const float* __restrict__ VALS, const float* __restrict__ W_f,
    const float* __restrict__ b_f, float* __restrict__ out)
{
    __shared__ float vs[HD * 10];   // [k][row], pad 10 (float2-aligned)
    const int t = threadIdx.x;
    const int row0 = blockIdx.x * 8;
    #pragma unroll
    for (int it = 0; it < 16; ++it) {
        int i = t + 256 * it;       // 0..4095
        int r = i >> 9, k = i & 511;
        vs[k * 10 + r] = VALS[(size_t)(row0 + r) * HD + k];
    }
    __syncthreads();
    const int j = t & 63, rg = t >> 6;   // rows rg*2, rg*2+1
    float acc0 = 0.f, acc1 = 0.f;
    for (int k = 0; k < 512; ++k) {
        float wv = W_f[k * 64 + j];
        float2 v = *(const float2*)&vs[k * 10 + rg * 2];
        acc0 = fmaf(v.x, wv, acc0);
        acc1 = fmaf(v.y, wv, acc1);
    }
    float bj = b_f[j];
    out[(size_t)(row0 + rg * 2 + 0) * ND + j] = acc0 + bj;
    out[(size_t)(row0 + rg * 2 + 1) * ND + j] = acc1 + bj;
}

// ---------------------------------------------------------------------------
extern "C" void kernel_launch(void* const* d_in, const int* in_sizes, int n_in,
                              void* d_out, int out_size, void* d_ws, size_t ws_size,
                              hipStream_t stream)
{
    const float* x     = (const float*)d_in[0];
    const float* bmat  = (const float*)d_in[1];
    const float* W_kvx = (const float*)d_in[2];
    const float* b_kvx = (const float*)d_in[3];
    const float* W_kvb = (const float*)d_in[4];
    const float* b_kvb = (const float*)d_in[5];
    const float* W_q   = (const float*)d_in[6];
    const float* b_q   = (const float*)d_in[7];
    const float* W_f   = (const float*)d_in[8];
    const float* b_f   = (const float*)d_in[9];
    float* out  = (float*)d_out;
    float* XQ   = (float*)d_ws;                   // 2048*1536 fp32 = 12.6 MB
    float* VALS = XQ + (size_t)NB * XQS;          // 2048*512  fp32 =  4 MB

    proj_kernel<<<dim3(32, 24), 256, 0, stream>>>(x, W_kvx, b_kvx, W_q, b_q, XQ);
    attn_kernel<<<NB, 256, 0, stream>>>(bmat, W_kvb, b_kvb, XQ, VALS);
    out_kernel<<<NB / 8, 256, 0, stream>>>(VALS, W_f, b_f, out);
}

// Round 2
// 105.468 us; speedup vs baseline: 1.1854x; 1.1854x over previous
//
#include <hip/hip_runtime.h>

// (B,P,D,H,DB) = (2048,128,64,8,10)
// Fully fused: proj -> attention core (algebraically factored) -> out GEMM.
//
// Factorization (P-loop never touches a 64-wide dot):
//   dots[p,h] = 0.125*(dot0[h] + sum_e b[p,e]*Wqkb[e,h])
//     dot0[h]   = sum_d (xk[h,d]+b_kvb_k) * q[h,d]
//     Wqkb[e,h] = sum_d W_kvb[e,h*64+d] * q[h,d]
//   softmax over h; A[h]=sum_p attn, S[e,h]=sum_p attn*b[p,e]
//   vals[h,d] = A[h]*(xv+b_kvb_v) + sum_e S[e,h]*W_kvb[e,512+h*64+d]
//   out = vals @ W_f + b_f
#define NDB 10

__global__ __launch_bounds__(256) void fused_attn(
    const float* __restrict__ x, const float* __restrict__ bmat,
    const float* __restrict__ W_kvx, const float* __restrict__ b_kvx,
    const float* __restrict__ W_kvb, const float* __restrict__ b_kvb,
    const float* __restrict__ W_q, const float* __restrict__ b_q,
    const float* __restrict__ W_f, const float* __restrict__ b_f,
    float* __restrict__ out)
{
    __shared__ float x_t[64][4];          //  1 KB  x transposed [k][r]
    __shared__ float bb_s[4][1280];       // 20 KB  b rows
    __shared__ float xp_s[4][1024];       // 16 KB  x@W_kvx + b_kvx + b_kvb
    __shared__ float q_s[4][512];         //  8 KB  x@W_q + b_q
    __shared__ float dot0_s[4][8];
    __shared__ float Wqkb_s[4][NDB][8];
    __shared__ float A_s[4][8];
    __shared__ float S_s[4][NDB][8];
    __shared__ float vals_s[512][4];      //  8 KB  transposed [f][r]
    __shared__ float pout[4][4][64];      //  4 KB  partial out [fs][r][j]

    const int t = threadIdx.x;
    const int b0 = blockIdx.x * 4;
    const int lane = t & 63;
    const int w = t >> 6;

    // ---- Phase A: stage x (transposed) + b ----
    x_t[t & 63][t >> 6] = x[b0 * 64 + t];            // coalesced read
    {
        const float4* src = (const float4*)(bmat + (size_t)b0 * 1280);
        float4* dst = (float4*)bb_s;
        #pragma unroll
        for (int it = 0; it < 5; ++it) dst[t + 256 * it] = src[t + 256 * it];
    }
    __syncthreads();

    // ---- Phase B: projections (weights read once per block, coalesced) ----
    {
        float accKV[4][4] = {};   // [r][c] for features c*256+t of kv
        float accQ[4][2] = {};    // [r][c] for features c*256+t of q
        const float* pkv = W_kvx + t;
        const float* pq  = W_q  + t;
        #pragma unroll 4
        for (int k = 0; k < 64; ++k) {
            float4 xv = *(const float4*)&x_t[k][0];   // broadcast ds_read_b128
            float xr[4] = {xv.x, xv.y, xv.z, xv.w};
            float wkv[4], wq[2];
            #pragma unroll
            for (int c = 0; c < 4; ++c) wkv[c] = pkv[k * 1024 + c * 256];
            #pragma unroll
            for (int c = 0; c < 2; ++c) wq[c] = pq[k * 512 + c * 256];
            #pragma unroll
            for (int r = 0; r < 4; ++r) {
                #pragma unroll
                for (int c = 0; c < 4; ++c) accKV[r][c] = fmaf(xr[r], wkv[c], accKV[r][c]);
                #pragma unroll
                for (int c = 0; c < 2; ++c) accQ[r][c]  = fmaf(xr[r], wq[c],  accQ[r][c]);
            }
        }
        #pragma unroll
        for (int c = 0; c < 4; ++c) {
            int f = c * 256 + t;
            float bias = b_kvx[f] + b_kvb[f];   // fold BOTH biases into xp
            #pragma unroll
            for (int rr = 0; rr < 4; ++rr) xp_s[rr][f] = accKV[rr][c] + bias;
        }
        #pragma unroll
        for (int c = 0; c < 2; ++c) {
            int fq = c * 256 + t;
            float bias = b_q[fq];
            #pragma unroll
            for (int rr = 0; rr < 4; ++rr) q_s[rr][fq] = accQ[rr][c] + bias;
        }
    }
    __syncthreads();

    const int r = w;   // wave w owns batch row b0+w for the attention core

    // ---- Phase C: dot0[h] and Wqkb[e][h] (8-lane-group dots) ----
    {
        int h = lane >> 3, i8 = lane & 7;
        float s = 0.f;
        #pragma unroll
        for (int j = 0; j < 8; ++j) {
            int d = h * 64 + i8 + j * 8;
            s = fmaf(xp_s[r][d], q_s[r][d], s);
        }
        s += __shfl_xor(s, 1); s += __shfl_xor(s, 2); s += __shfl_xor(s, 4);
        if (i8 == 0) dot0_s[r][h] = s;
    }
    {
        int g = lane >> 3, l = lane & 7;   // group g computes h=g for each e
        #pragma unroll
        for (int e = 0; e < NDB; ++e) {
            float s = 0.f;
            #pragma unroll
            for (int m = 0; m < 8; ++m) {
                int d = g * 64 + l + m * 8;
                s = fmaf(W_kvb[e * 1024 + d], q_s[r][d], s);
            }
            s += __shfl_xor(s, 1); s += __shfl_xor(s, 2); s += __shfl_xor(s, 4);
            if (l == 0) Wqkb_s[r][e][g] = s;
        }
    }
    __syncthreads();

    // ---- Phase C2: dots + softmax(h) + A/S accumulation (in-wave) ----
    {
        int h = lane & 7, pg = lane >> 3;
        float aA = 0.f, aS[NDB];
        #pragma unroll
        for (int e = 0; e < NDB; ++e) aS[e] = 0.f;
        #pragma unroll 4
        for (int it = 0; it < 16; ++it) {
            int p = pg + 8 * it;
            float dot = dot0_s[r][h];
            #pragma unroll
            for (int e = 0; e < NDB; ++e)
                dot = fmaf(bb_s[r][p * NDB + e], Wqkb_s[r][e][h], dot);
            dot *= 0.125f;
            float m = dot;
            m = fmaxf(m, __shfl_xor(m, 1));
            m = fmaxf(m, __shfl_xor(m, 2));
            m = fmaxf(m, __shfl_xor(m, 4));
            float ex = __expf(dot - m);
            float sum = ex;
            sum += __shfl_xor(sum, 1); sum += __shfl_xor(sum, 2); sum += __shfl_xor(sum, 4);
            float at = ex * __builtin_amdgcn_rcpf(sum);
            aA += at;
            #pragma unroll
            for (int e = 0; e < NDB; ++e) aS[e] = fmaf(at, bb_s[r][p * NDB + e], aS[e]);
        }
        aA += __shfl_xor(aA, 8); aA += __shfl_xor(aA, 16); aA += __shfl_xor(aA, 32);
        #pragma unroll
        for (int e = 0; e < NDB; ++e) {
            aS[e] += __shfl_xor(aS[e], 8);
            aS[e] += __shfl_xor(aS[e], 16);
            aS[e] += __shfl_xor(aS[e], 32);
        }
        if (pg == 0) {
            A_s[r][h] = aA;
            #pragma unroll
            for (int e = 0; e < NDB; ++e) S_s[r][e][h] = aS[e];
        }
    }
    __syncthreads();

    // ---- vals -> vals_s transposed [f][r] ----
    #pragma unroll
    for (int i = 0; i < 8; ++i) {
        int f = lane + 64 * i;             // h = f>>6 = i
        float v = A_s[r][i] * xp_s[r][512 + f];
        #pragma unroll
        for (int e = 0; e < NDB; ++e)
            v = fmaf(S_s[r][e][i], W_kvb[e * 1024 + 512 + f], v);
        vals_s[f][r] = v;
    }
    __syncthreads();

    // ---- Phase D: out = vals @ W_f + b_f (W_f read once per block) ----
    {
        const int j = t & 63, fs = t >> 6;
        float acc0 = 0.f, acc1 = 0.f, acc2 = 0.f, acc3 = 0.f;
        #pragma unroll 4
        for (int fi = 0; fi < 128; ++fi) {
            int f = fs * 128 + fi;
            float4 v = *(const float4*)&vals_s[f][0];  // broadcast ds_read_b128
            float wf = W_f[f * 64 + j];                // coalesced, L2-hit
            acc0 = fmaf(v.x, wf, acc0);
            acc1 = fmaf(v.y, wf, acc1);
            acc2 = fmaf(v.z, wf, acc2);
            acc3 = fmaf(v.w, wf, acc3);
        }
        pout[fs][0][j] = acc0; pout[fs][1][j] = acc1;
        pout[fs][2][j] = acc2; pout[fs][3][j] = acc3;
    }
    __syncthreads();
    {
        const int rr = t >> 6, j = t & 63;
        float o = pout[0][rr][j] + pout[1][rr][j] + pout[2][rr][j] + pout[3][rr][j] + b_f[j];
        out[(size_t)(b0 + rr) * 64 + j] = o;
    }
}

extern "C" void kernel_launch(void* const* d_in, const int* in_sizes, int n_in,
                              void* d_out, int out_size, void* d_ws, size_t ws_size,
                              hipStream_t stream)
{
    const float* x     = (const float*)d_in[0];
    const float* bmat  = (const float*)d_in[1];
    const float* W_kvx = (const float*)d_in[2];
    const float* b_kvx = (const float*)d_in[3];
    const float* W_kvb = (const float*)d_in[4];
    const float* b_kvb = (const float*)d_in[5];
    const float* W_q   = (const float*)d_in[6];
    const float* b_q   = (const float*)d_in[7];
    const float* W_f   = (const float*)d_in[8];
    const float* b_f   = (const float*)d_in[9];
    float* out = (float*)d_out;

    fused_attn<<<512, 256, 0, stream>>>(x, bmat, W_kvx, b_kvx, W_kvb, b_kvb,
                                        W_q, b_q, W_f, b_f, out);
}